// Round 18
// baseline (371.252 us; speedup 1.0000x reference)
//
#include <hip/hip_runtime.h>

#define NP 131072
#define C 256
#define T 16
#define BB 8
constexpr float EPS = 1e-5f;

// ---------------- ws layout (floats) ----------------
constexpr int NT       = NP * T;              // 2,097,152
constexpr int OFF_DM   = 0;                   // dm softmax [N,T]
constexpr int OFF_Z    = NT;                  // z [B,T]
constexpr int OFF_S    = OFF_Z + BB * T;      // s [B,T,C] (unnormalized; rz folded downstream)
constexpr int OFF_DMP  = OFF_S + BB * T * C;  // dmsum partials [8][B*T]
constexpr int OFF_SSP  = OFF_DMP + 8 * BB * T;// sumsq partials [8][C]
constexpr int OFF_KEYS = OFF_SSP + 8 * C;
constexpr int OFF_QRS  = OFF_KEYS + BB * T * C;
constexpr int OFF_VALS = OFF_QRS + BB * T * C;
constexpr int OFF_TM   = OFF_VALS + BB * T * C;
constexpr int OFF_TP   = OFF_TM + BB * T * C;
constexpr int OFF_U    = OFF_TP + BB * T * C;
constexpr int OFF_V    = OFF_U + BB * T * C;
constexpr int OFF_CMB  = OFF_V + BB * T * C;  // 5 x [C,C]
constexpr int OFF_BNA  = OFF_CMB + 5 * C * C; // [C]
constexpr int OFF_BNB  = OFF_BNA + C;         // [C]

constexpr int RPB = 64;       // rows per block for kDE / kF
constexpr int AB_RPB = 256;   // kAB3: R12-proven best
constexpr int ZERO_N = BB * T + BB * T * C + 8 * BB * T + 8 * C;

// reduce-scatter 64 values across the 64 lanes of a wave.
__device__ inline float reduceScatter64(const float (&a)[64], int lane) {
  float b32[32];
  {
    bool hi = (lane & 32) != 0;
#pragma unroll
    for (int i = 0; i < 32; ++i) {
      float mine = hi ? a[i + 32] : a[i];
      float th   = hi ? a[i]      : a[i + 32];
      b32[i] = mine + __shfl_xor(th, 32);
    }
  }
  float b16[16];
  {
    bool hi = (lane & 16) != 0;
#pragma unroll
    for (int i = 0; i < 16; ++i) {
      float mine = hi ? b32[i + 16] : b32[i];
      float th   = hi ? b32[i]      : b32[i + 16];
      b16[i] = mine + __shfl_xor(th, 16);
    }
  }
  float b8[8];
  {
    bool hi = (lane & 8) != 0;
#pragma unroll
    for (int i = 0; i < 8; ++i) {
      float mine = hi ? b16[i + 8] : b16[i];
      float th   = hi ? b16[i]     : b16[i + 8];
      b8[i] = mine + __shfl_xor(th, 8);
    }
  }
  float b4[4];
  {
    bool hi = (lane & 4) != 0;
#pragma unroll
    for (int i = 0; i < 4; ++i) {
      float mine = hi ? b8[i + 4] : b8[i];
      float th   = hi ? b8[i]     : b8[i + 4];
      b4[i] = mine + __shfl_xor(th, 4);
    }
  }
  float b2[2];
  {
    bool hi = (lane & 2) != 0;
#pragma unroll
    for (int i = 0; i < 2; ++i) {
      float mine = hi ? b4[i + 2] : b4[i];
      float th   = hi ? b4[i]     : b4[i + 2];
      b2[i] = mine + __shfl_xor(th, 2);
    }
  }
  bool hi = (lane & 1) != 0;
  float mine = hi ? b2[1] : b2[0];
  float th   = hi ? b2[0] : b2[1];
  return mine + __shfl_xor(th, 1);
}

// ---------------- K0: zero accumulators ----------------
__global__ __launch_bounds__(256) void k0_init(float* __restrict__ ws) {
  int i = blockIdx.x * 256 + threadIdx.x;
  if (i < ZERO_N) ws[OFF_Z + i] = 0.f;
}

// flush helper for boundary blocks
__device__ inline void s_flush(float4 (&acc)[T], int cur_b, int lane,
                               float* __restrict__ s) {
#pragma unroll
  for (int t = 0; t < T; ++t) {
    float* p = s + ((size_t)cur_b * T + t) * C + 4 * lane;
    atomicAdd(p + 0, acc[t].x);
    atomicAdd(p + 1, acc[t].y);
    atomicAdd(p + 2, acc[t].z);
    atomicAdd(p + 3, acc[t].w);
    acc[t] = make_float4(0.f, 0.f, 0.f, 0.f);
  }
}

// ---------------- kAB3: single-x-pass fused e/z/s' + register prefetch ----------------
// R18: software-pipeline xs loads (next step prefetched into regs while current
// computes). +16 VGPR is free: grid-limited at 2 blocks/CU (512 blocks).
// Plain launch_bounds(256): do NOT add min-waves (R7: forced spill).
__global__ __launch_bounds__(256) void kAB3(const float* __restrict__ xf,
    const int* __restrict__ bids, const float* __restrict__ Wk,
    float* __restrict__ z, float* __restrict__ s) {
  __shared__ float4 wk_sacc[T * 64];    // 16 KB: wk4 in loop; sacc after
  __shared__ float e_lds[AB_RPB][T];    // 16 KB (wave-local rows)
  __shared__ float zred[4][64];         // 1 KB
  __shared__ int bid_lds[AB_RPB];       // 1 KB
  float4* wk4 = wk_sacc;
  float* sacc = (float*)wk_sacc;
  const int tid = threadIdx.x;
  const int n0 = blockIdx.x * AB_RPB;
  for (int i = tid; i < T * 64; i += 256) {
    int t = i >> 6, q = i & 63;
    wk4[i] = make_float4(Wk[(4 * q + 0) * T + t], Wk[(4 * q + 1) * T + t],
                         Wk[(4 * q + 2) * T + t], Wk[(4 * q + 3) * T + t]);
  }
  for (int i = tid; i < AB_RPB; i += 256) bid_lds[i] = bids[n0 + i];
  __syncthreads();
  const int wave = tid >> 6, lane = tid & 63;
  const int rr = lane >> 4, tt = lane & 15;
  const float4* xf4 = (const float4*)xf;
  const bool blockUni = (bid_lds[0] == bid_lds[AB_RPB - 1]);
  const int WROWS = AB_RPB / 4;          // rows per wave = 64
  const int NSTEP = WROWS / 4;           // 16

  int cur_b = bid_lds[wave * WROWS + rr];
  float zacc = 0.f;
  float4 acc2[T];
#pragma unroll
  for (int t = 0; t < T; ++t) acc2[t] = make_float4(0.f, 0.f, 0.f, 0.f);
  int cb2 = bid_lds[wave * WROWS];

  // preload step 0
  float4 xs[4];
#pragma unroll
  for (int r = 0; r < 4; ++r)
    xs[r] = xf4[(size_t)(n0 + wave * WROWS + r) * 64 + lane];

  for (int stp = 0; stp < NSTEP; ++stp) {
    const int rb = wave * WROWS + stp * 4;
    // ---- prefetch next step (clamped on last) ----
    float4 xn[4];
    const int rbn = (stp + 1 < NSTEP) ? rb + 4 : rb;
#pragma unroll
    for (int r = 0; r < 4; ++r)
      xn[r] = xf4[(size_t)(n0 + rbn + r) * 64 + lane];
    // ---- logits ----
    float acc[64];
#pragma unroll
    for (int t = 0; t < T; ++t) {
      float4 w = wk4[t * 64 + lane];
      acc[0 * 16 + t] = xs[0].x * w.x + xs[0].y * w.y + xs[0].z * w.z + xs[0].w * w.w;
      acc[1 * 16 + t] = xs[1].x * w.x + xs[1].y * w.y + xs[1].z * w.z + xs[1].w * w.w;
      acc[2 * 16 + t] = xs[2].x * w.x + xs[2].y * w.y + xs[2].z * w.z + xs[2].w * w.w;
      acc[3 * 16 + t] = xs[3].x * w.x + xs[3].y * w.y + xs[3].z * w.z + xs[3].w * w.w;
    }
    float rv = reduceScatter64(acc, lane);
    float ev = __expf(rv);
    e_lds[rb + rr][tt] = ev;
    if (!blockUni) {
      int b = bid_lds[rb + rr];
      if (b != cur_b) { atomicAdd(&z[cur_b * T + tt], zacc); zacc = 0.f; cur_b = b; }
    }
    zacc += ev;
    bool uni = blockUni || (bid_lds[rb] == cb2 && bid_lds[rb + 3] == cb2);
    if (uni) {
#pragma unroll
      for (int tq = 0; tq < 4; ++tq) {
#pragma unroll
        for (int r = 0; r < 4; ++r) {
          float4 ev4 = ((const float4*)&e_lds[rb + r][0])[tq];
          acc2[tq * 4 + 0].x = fmaf(ev4.x, xs[r].x, acc2[tq * 4 + 0].x);
          acc2[tq * 4 + 0].y = fmaf(ev4.x, xs[r].y, acc2[tq * 4 + 0].y);
          acc2[tq * 4 + 0].z = fmaf(ev4.x, xs[r].z, acc2[tq * 4 + 0].z);
          acc2[tq * 4 + 0].w = fmaf(ev4.x, xs[r].w, acc2[tq * 4 + 0].w);
          acc2[tq * 4 + 1].x = fmaf(ev4.y, xs[r].x, acc2[tq * 4 + 1].x);
          acc2[tq * 4 + 1].y = fmaf(ev4.y, xs[r].y, acc2[tq * 4 + 1].y);
          acc2[tq * 4 + 1].z = fmaf(ev4.y, xs[r].z, acc2[tq * 4 + 1].z);
          acc2[tq * 4 + 1].w = fmaf(ev4.y, xs[r].w, acc2[tq * 4 + 1].w);
          acc2[tq * 4 + 2].x = fmaf(ev4.z, xs[r].x, acc2[tq * 4 + 2].x);
          acc2[tq * 4 + 2].y = fmaf(ev4.z, xs[r].y, acc2[tq * 4 + 2].y);
          acc2[tq * 4 + 2].z = fmaf(ev4.z, xs[r].z, acc2[tq * 4 + 2].z);
          acc2[tq * 4 + 2].w = fmaf(ev4.z, xs[r].w, acc2[tq * 4 + 2].w);
          acc2[tq * 4 + 3].x = fmaf(ev4.w, xs[r].x, acc2[tq * 4 + 3].x);
          acc2[tq * 4 + 3].y = fmaf(ev4.w, xs[r].y, acc2[tq * 4 + 3].y);
          acc2[tq * 4 + 3].z = fmaf(ev4.w, xs[r].z, acc2[tq * 4 + 3].z);
          acc2[tq * 4 + 3].w = fmaf(ev4.w, xs[r].w, acc2[tq * 4 + 3].w);
        }
      }
    } else {
#pragma unroll
      for (int r = 0; r < 4; ++r) {
        int b = bid_lds[rb + r];
        if (b != cb2) { s_flush(acc2, cb2, lane, s); cb2 = b; }
#pragma unroll
        for (int t = 0; t < T; ++t) {
          float ev2 = e_lds[rb + r][t];
          acc2[t].x = fmaf(ev2, xs[r].x, acc2[t].x);
          acc2[t].y = fmaf(ev2, xs[r].y, acc2[t].y);
          acc2[t].z = fmaf(ev2, xs[r].z, acc2[t].z);
          acc2[t].w = fmaf(ev2, xs[r].w, acc2[t].w);
        }
      }
    }
    // ---- rotate prefetched regs ----
#pragma unroll
    for (int r = 0; r < 4; ++r) xs[r] = xn[r];
  }
  if (blockUni) zred[wave][lane] = zacc;
  else atomicAdd(&z[cur_b * T + tt], zacc);
  __syncthreads();
  if (blockUni) {
    if (tid < 64) {
      float zt = zred[0][tid] + zred[1][tid] + zred[2][tid] + zred[3][tid];
      zt += __shfl_xor(zt, 16);
      zt += __shfl_xor(zt, 32);
      if (tid < 16) atomicAdd(&z[bid_lds[0] * T + tid], zt);
    }
    for (int i = tid; i < T * C; i += 256) sacc[i] = 0.f;
    __syncthreads();
#pragma unroll
    for (int t = 0; t < T; ++t) {
      float* p = sacc + t * C + 4 * lane;
      atomicAdd(p + 0, acc2[t].x);
      atomicAdd(p + 1, acc2[t].y);
      atomicAdd(p + 2, acc2[t].z);
      atomicAdd(p + 3, acc2[t].w);
    }
    __syncthreads();
    int b0 = bid_lds[0];
    for (int t = 0; t < T; ++t)
      atomicAdd(&s[((size_t)b0 * T + t) * C + tid], sacc[t * C + tid]);
  } else {
    s_flush(acc2, cb2, lane, s);
  }
}

// ---------------- K4a: combined weight mats ----------------
__global__ __launch_bounds__(256) void k4a_cmb(const float* __restrict__ Wv,
    const float* __restrict__ Wke, const float* __restrict__ Wqe,
    const float* __restrict__ Wt, const float* __restrict__ Wemb,
    const float* __restrict__ Wq, float* __restrict__ cmb) {
  int mm = blockIdx.x, r = blockIdx.y;
  const float* A = (mm == 0) ? Wv : (mm == 1) ? Wke : (mm == 2) ? Wqe : Wt;
  const float* Bm = (mm == 4) ? Wemb : Wq;
  bool modeT = (mm == 4);
  __shared__ float a_lds[8 * C];
  int o0 = r * 8;
  for (int i = threadIdx.x; i < 8 * C; i += 256) a_lds[i] = A[o0 * C + i];
  __syncthreads();
  int cp = threadIdx.x;
  float acc[8];
#pragma unroll
  for (int oo = 0; oo < 8; ++oo) acc[oo] = 0.f;
  for (int c = 0; c < C; ++c) {
    float bb = modeT ? Bm[c * C + cp] : Bm[cp * C + c];
#pragma unroll
    for (int oo = 0; oo < 8; ++oo) acc[oo] = fmaf(a_lds[oo * C + c], bb, acc[oo]);
  }
  float* outp = cmb + mm * C * C;
#pragma unroll
  for (int oo = 0; oo < 8; ++oo) outp[(o0 + oo) * C + cp] = acc[oo];
}

// ---------------- K4b: keys/qrs/vals (z-normalization folded in) ----------------
__global__ __launch_bounds__(256) void k4b_kqv(const float* __restrict__ cmb,
    const float* __restrict__ s, const float* __restrict__ z,
    float* __restrict__ keys, float* __restrict__ qrs, float* __restrict__ vals) {
  int b = blockIdx.x, mat = blockIdx.y, q = blockIdx.z;
  const int midx0 = (mat == 0) ? 1 : (mat == 1) ? 2 : 0;
  const float* M = cmb + midx0 * C * C;
  float* outp = (mat == 0) ? keys : (mat == 1) ? qrs : vals;
  __shared__ float s_lds[T * C];
  __shared__ float rz[T];
  if (threadIdx.x < T) rz[threadIdx.x] = 1.f / z[b * T + threadIdx.x];
  __syncthreads();
  for (int i = threadIdx.x; i < T * C; i += 256)
    s_lds[i] = s[(size_t)b * T * C + i] * rz[i >> 8];
  __syncthreads();
  int o = q * 64 + (threadIdx.x & 63);
  int tg = threadIdx.x >> 6;
  float acc[4] = {0.f, 0.f, 0.f, 0.f};
  for (int c = 0; c < C; ++c) {
    float m = M[o * C + c];
#pragma unroll
    for (int tt = 0; tt < 4; ++tt) acc[tt] = fmaf(m, s_lds[(tg * 4 + tt) * C + c], acc[tt]);
  }
#pragma unroll
  for (int tt = 0; tt < 4; ++tt)
    outp[((size_t)b * T + tg * 4 + tt) * C + o] = acc[tt];
}

// ---------------- K4c: token attention + T_middle ----------------
__global__ __launch_bounds__(256) void k4c_att(const float* __restrict__ keys,
    const float* __restrict__ qrs, const float* __restrict__ vals,
    float* __restrict__ tm) {
  int b = blockIdx.x;
  __shared__ float k_lds[T * 257];
  __shared__ float q_lds[T * 257];
  __shared__ float v_lds[T * 257];
  __shared__ float att[T * 17];
  int tid = threadIdx.x;
  for (int i = tid; i < T * C; i += 256) {
    int t = i >> 8, c = i & 255;
    k_lds[t * 257 + c] = keys[((size_t)b * T + t) * C + c];
    q_lds[t * 257 + c] = qrs[((size_t)b * T + t) * C + c];
    v_lds[t * 257 + c] = vals[((size_t)b * T + t) * C + c];
  }
  __syncthreads();
  {
    int t = tid >> 4, s2 = tid & 15;
    float acc = 0.f;
    for (int o = 0; o < C; ++o) acc = fmaf(k_lds[t * 257 + o], q_lds[s2 * 257 + o], acc);
    att[t * 17 + s2] = acc;
  }
  __syncthreads();
  if (tid < T) {
    float m = -1e30f;
    for (int s2 = 0; s2 < T; ++s2) m = fmaxf(m, att[tid * 17 + s2]);
    float sum = 0.f;
    for (int s2 = 0; s2 < T; ++s2) {
      float ee = __expf(att[tid * 17 + s2] - m);
      att[tid * 17 + s2] = ee;
      sum += ee;
    }
    float inv = 1.f / sum;
    for (int s2 = 0; s2 < T; ++s2) att[tid * 17 + s2] *= inv;
  }
  __syncthreads();
  for (int t = 0; t < T; ++t) {
    float acc = 0.f;
#pragma unroll
    for (int s2 = 0; s2 < T; ++s2) acc = fmaf(att[t * 17 + s2], v_lds[s2 * 257 + tid], acc);
    tm[((size_t)b * T + t) * C + tid] = acc;
  }
}

// ---------------- K4d: T_P = At*(s/z) + Ae*Tm ----------------
__global__ __launch_bounds__(256) void k4d_tp(const float* __restrict__ cmb,
    const float* __restrict__ s, const float* __restrict__ z,
    const float* __restrict__ tm, float* __restrict__ tp) {
  int b = blockIdx.x, q = blockIdx.y;
  const float* At = cmb + 3 * C * C;
  const float* Ae = cmb + 4 * C * C;
  __shared__ float s_lds[T * C];
  __shared__ float tm_lds[T * C];
  __shared__ float rz[T];
  if (threadIdx.x < T) rz[threadIdx.x] = 1.f / z[b * T + threadIdx.x];
  __syncthreads();
  for (int i = threadIdx.x; i < T * C; i += 256) {
    s_lds[i] = s[(size_t)b * T * C + i] * rz[i >> 8];
    tm_lds[i] = tm[(size_t)b * T * C + i];
  }
  __syncthreads();
  int o = q * 64 + (threadIdx.x & 63);
  int tg = threadIdx.x >> 6;
  float acc[4] = {0.f, 0.f, 0.f, 0.f};
  for (int c = 0; c < C; ++c) {
    float a1 = At[o * C + c], a2 = Ae[o * C + c];
#pragma unroll
    for (int tt = 0; tt < 4; ++tt) {
      int t = tg * 4 + tt;
      acc[tt] = fmaf(a1, s_lds[t * C + c], fmaf(a2, tm_lds[t * C + c], acc[tt]));
    }
  }
#pragma unroll
  for (int tt = 0; tt < 4; ++tt)
    tp[((size_t)b * T + tg * 4 + tt) * C + o] = acc[tt];
}

// ---------------- K4e: U = Wp*T_P ; V = T_P^T * Wtrans ----------------
__global__ __launch_bounds__(256) void k4e_uv(const float* __restrict__ Wp,
    const float* __restrict__ Wtrans, const float* __restrict__ tp,
    float* __restrict__ u, float* __restrict__ v) {
  int b = blockIdx.x, mat = blockIdx.y, q = blockIdx.z;
  __shared__ float tp_lds[T * C];
  for (int i = threadIdx.x; i < T * C; i += 256) tp_lds[i] = tp[(size_t)b * T * C + i];
  __syncthreads();
  int o = q * 64 + (threadIdx.x & 63);
  int tg = threadIdx.x >> 6;
  float acc[4] = {0.f, 0.f, 0.f, 0.f};
  for (int c = 0; c < C; ++c) {
    float w = mat ? Wtrans[c * C + o] : Wp[o * C + c];
#pragma unroll
    for (int tt = 0; tt < 4; ++tt) acc[tt] = fmaf(w, tp_lds[(tg * 4 + tt) * C + c], acc[tt]);
  }
  float* outp = mat ? v : u;
#pragma unroll
  for (int tt = 0; tt < 4; ++tt)
    outp[((size_t)b * T + tg * 4 + tt) * C + o] = acc[tt];
}

// ---------------- kDE: dm = softmax(x.U) ; xr = dm.V ; sumsq, dmsum (RPB=64) ----------------
__global__ __launch_bounds__(256) void kDE(const float* __restrict__ xf,
    const int* __restrict__ bids, const float* __restrict__ u,
    const float* __restrict__ v, float* __restrict__ dmo,
    float* __restrict__ dmsum_p, float* __restrict__ sumsq_p) {
  __shared__ float4 u4[T * 64];
  __shared__ float4 v4[T * 64];
  __shared__ float4 ss4[4][64];
  __shared__ float zred[4][64];
  __shared__ int bid_lds[RPB];
  const int tid = threadIdx.x;
  const int n0 = blockIdx.x * RPB;
  const int b0 = bids[n0];
  const int part = blockIdx.x & 7;
  for (int i = tid; i < T * 64; i += 256) {
    u4[i] = ((const float4*)(u + (size_t)b0 * T * C))[i];
    v4[i] = ((const float4*)(v + (size_t)b0 * T * C))[i];
  }
  if (tid < RPB) bid_lds[tid] = bids[n0 + tid];
  __syncthreads();
  const int wave = tid >> 6, lane = tid & 63;
  const int rr = lane >> 4, tt = lane & 15;
  const float4* xf4 = (const float4*)xf;
  const bool blockUni = (bid_lds[0] == bid_lds[RPB - 1]);
  float4 sqacc = make_float4(0.f, 0.f, 0.f, 0.f);
  float dmacc = 0.f;
  int cur_b = bid_lds[wave * 16 + rr];
  for (int stp = 0; stp < 4; ++stp) {
    const int rb = wave * 16 + stp * 4;
    float4 x0 = xf4[(size_t)(n0 + rb + 0) * 64 + lane];
    float4 x1 = xf4[(size_t)(n0 + rb + 1) * 64 + lane];
    float4 x2 = xf4[(size_t)(n0 + rb + 2) * 64 + lane];
    float4 x3 = xf4[(size_t)(n0 + rb + 3) * 64 + lane];
    float acc[64];
    bool fast = blockUni || ((bid_lds[rb] == b0) && (bid_lds[rb + 3] == b0));
    if (fast) {
#pragma unroll
      for (int t = 0; t < T; ++t) {
        float4 w = u4[t * 64 + lane];
        acc[0 * 16 + t] = x0.x * w.x + x0.y * w.y + x0.z * w.z + x0.w * w.w;
        acc[1 * 16 + t] = x1.x * w.x + x1.y * w.y + x1.z * w.z + x1.w * w.w;
        acc[2 * 16 + t] = x2.x * w.x + x2.y * w.y + x2.z * w.z + x2.w * w.w;
        acc[3 * 16 + t] = x3.x * w.x + x3.y * w.y + x3.z * w.z + x3.w * w.w;
      }
    } else {
      int br0 = bid_lds[rb + 0], br1 = bid_lds[rb + 1];
      int br2 = bid_lds[rb + 2], br3 = bid_lds[rb + 3];
#pragma unroll
      for (int t = 0; t < T; ++t) {
        float4 w0 = ((const float4*)(u + ((size_t)br0 * T + t) * C))[lane];
        float4 w1 = ((const float4*)(u + ((size_t)br1 * T + t) * C))[lane];
        float4 w2 = ((const float4*)(u + ((size_t)br2 * T + t) * C))[lane];
        float4 w3 = ((const float4*)(u + ((size_t)br3 * T + t) * C))[lane];
        acc[0 * 16 + t] = x0.x * w0.x + x0.y * w0.y + x0.z * w0.z + x0.w * w0.w;
        acc[1 * 16 + t] = x1.x * w1.x + x1.y * w1.y + x1.z * w1.z + x1.w * w1.w;
        acc[2 * 16 + t] = x2.x * w2.x + x2.y * w2.y + x2.z * w2.z + x2.w * w2.w;
        acc[3 * 16 + t] = x3.x * w3.x + x3.y * w3.y + x3.z * w3.z + x3.w * w3.w;
      }
    }
    float S = reduceScatter64(acc, lane);
    float mx = S;
#pragma unroll
    for (int m = 1; m < 16; m <<= 1) mx = fmaxf(mx, __shfl_xor(mx, m));
    float ev = __expf(S - mx);
    float sm = ev;
#pragma unroll
    for (int m = 1; m < 16; m <<= 1) sm += __shfl_xor(sm, m);
    float dmv = ev / sm;
    int row = n0 + rb + rr;
    dmo[(size_t)row * T + tt] = dmv;
    if (!blockUni) {
      int b = bid_lds[rb + rr];
      if (b != cur_b) { atomicAdd(&dmsum_p[part * BB * T + cur_b * T + tt], dmacc); dmacc = 0.f; cur_b = b; }
    }
    dmacc += dmv;
#pragma unroll
    for (int r = 0; r < 4; ++r) {
      int br = blockUni ? b0 : bid_lds[rb + r];
      float4 xr = make_float4(0.f, 0.f, 0.f, 0.f);
      if (br == b0) {
#pragma unroll
        for (int t = 0; t < T; ++t) {
          float d = __shfl(dmv, r * 16 + t);
          float4 vv = v4[t * 64 + lane];
          xr.x = fmaf(d, vv.x, xr.x); xr.y = fmaf(d, vv.y, xr.y);
          xr.z = fmaf(d, vv.z, xr.z); xr.w = fmaf(d, vv.w, xr.w);
        }
      } else {
#pragma unroll
        for (int t = 0; t < T; ++t) {
          float d = __shfl(dmv, r * 16 + t);
          float4 vv = ((const float4*)(v + ((size_t)br * T + t) * C))[lane];
          xr.x = fmaf(d, vv.x, xr.x); xr.y = fmaf(d, vv.y, xr.y);
          xr.z = fmaf(d, vv.z, xr.z); xr.w = fmaf(d, vv.w, xr.w);
        }
      }
      sqacc.x = fmaf(xr.x, xr.x, sqacc.x); sqacc.y = fmaf(xr.y, xr.y, sqacc.y);
      sqacc.z = fmaf(xr.z, xr.z, sqacc.z); sqacc.w = fmaf(xr.w, xr.w, sqacc.w);
    }
  }
  if (blockUni) zred[wave][lane] = dmacc;
  else atomicAdd(&dmsum_p[part * BB * T + cur_b * T + tt], dmacc);
  ss4[wave][lane] = sqacc;
  __syncthreads();
  if (blockUni && tid < 64) {
    float zt = zred[0][tid] + zred[1][tid] + zred[2][tid] + zred[3][tid];
    zt += __shfl_xor(zt, 16);
    zt += __shfl_xor(zt, 32);
    if (tid < 16) atomicAdd(&dmsum_p[part * BB * T + b0 * T + tid], zt);
  }
  {
    int l = tid >> 2, k = tid & 3;
    float vsum = ((const float*)&ss4[0][l])[k] + ((const float*)&ss4[1][l])[k] +
                 ((const float*)&ss4[2][l])[k] + ((const float*)&ss4[3][l])[k];
    atomicAdd(&sumsq_p[part * C + tid], vsum);
  }
}

// ---------------- K7: BN params (folds partials) ----------------
__global__ __launch_bounds__(256) void k7_bn(const float* __restrict__ dmsum_p,
    const float* __restrict__ sumsq_p, const float* __restrict__ v,
    const float* __restrict__ gamma, const float* __restrict__ beta,
    float* __restrict__ bn_a, float* __restrict__ bn_b) {
  int o = threadIdx.x;
  float mean = 0.f;
  for (int i = 0; i < BB * T; ++i) {
    float ds = 0.f;
#pragma unroll
    for (int p = 0; p < 8; ++p) ds += dmsum_p[p * BB * T + i];
    mean = fmaf(ds, v[(size_t)i * C + o], mean);
  }
  mean *= (1.f / NP);
  float ss = 0.f;
#pragma unroll
  for (int p = 0; p < 8; ++p) ss += sumsq_p[p * C + o];
  float var = ss * (1.f / NP) - mean * mean;
  float a = gamma[o] * rsqrtf(var + EPS);
  bn_a[o] = a;
  bn_b[o] = beta[o] - a * mean;
}

// ---------------- kF: out = x_f + relu(a*xr + b) ----------------
__global__ __launch_bounds__(256) void kF_out(const float* __restrict__ xf,
    const int* __restrict__ bids, const float* __restrict__ dm,
    const float* __restrict__ v, const float* __restrict__ bn_a,
    const float* __restrict__ bn_b, float* __restrict__ out) {
  __shared__ float4 v4[T * 64];
  __shared__ float dm_lds[RPB][17];
  __shared__ int bid_lds[RPB];
  const int tid = threadIdx.x;
  const int n0 = blockIdx.x * RPB;
  const int b0 = bids[n0];
  for (int i = tid; i < T * 64; i += 256)
    v4[i] = ((const float4*)(v + (size_t)b0 * T * C))[i];
  {
    float4 d4 = ((const float4*)(dm + (size_t)n0 * T))[tid];
    int r = tid >> 2, c0 = (4 * tid) & 15;
    dm_lds[r][c0] = d4.x; dm_lds[r][c0 + 1] = d4.y;
    dm_lds[r][c0 + 2] = d4.z; dm_lds[r][c0 + 3] = d4.w;
  }
  if (tid < RPB) bid_lds[tid] = bids[n0 + tid];
  __syncthreads();
  const int wave = tid >> 6, lane = tid & 63;
  float4 a4 = ((const float4*)bn_a)[lane];
  float4 b4 = ((const float4*)bn_b)[lane];
  const float4* xf4 = (const float4*)xf;
  float4* out4 = (float4*)out;
  for (int stp = 0; stp < 4; ++stp) {
    const int rb = wave * 16 + stp * 4;
    float4 x0 = xf4[(size_t)(n0 + rb + 0) * 64 + lane];
    float4 x1 = xf4[(size_t)(n0 + rb + 1) * 64 + lane];
    float4 x2 = xf4[(size_t)(n0 + rb + 2) * 64 + lane];
    float4 x3 = xf4[(size_t)(n0 + rb + 3) * 64 + lane];
    float4 acc0 = {0, 0, 0, 0}, acc1 = {0, 0, 0, 0}, acc2 = {0, 0, 0, 0}, acc3 = {0, 0, 0, 0};
    bool fast = (bid_lds[rb] == b0) && (bid_lds[rb + 3] == b0);
    if (fast) {
#pragma unroll
      for (int t = 0; t < T; ++t) {
        float4 vv = v4[t * 64 + lane];
        float d0 = dm_lds[rb + 0][t], d1 = dm_lds[rb + 1][t];
        float d2 = dm_lds[rb + 2][t], d3 = dm_lds[rb + 3][t];
        acc0.x = fmaf(d0, vv.x, acc0.x); acc0.y = fmaf(d0, vv.y, acc0.y);
        acc0.z = fmaf(d0, vv.z, acc0.z); acc0.w = fmaf(d0, vv.w, acc0.w);
        acc1.x = fmaf(d1, vv.x, acc1.x); acc1.y = fmaf(d1, vv.y, acc1.y);
        acc1.z = fmaf(d1, vv.z, acc1.z); acc1.w = fmaf(d1, vv.w, acc1.w);
        acc2.x = fmaf(d2, vv.x, acc2.x); acc2.y = fmaf(d2, vv.y, acc2.y);
        acc2.z = fmaf(d2, vv.z, acc2.z); acc2.w = fmaf(d2, vv.w, acc2.w);
        acc3.x = fmaf(d3, vv.x, acc3.x); acc3.y = fmaf(d3, vv.y, acc3.y);
        acc3.z = fmaf(d3, vv.z, acc3.z); acc3.w = fmaf(d3, vv.w, acc3.w);
      }
    } else {
      int br0 = bid_lds[rb + 0], br1 = bid_lds[rb + 1];
      int br2 = bid_lds[rb + 2], br3 = bid_lds[rb + 3];
#pragma unroll
      for (int t = 0; t < T; ++t) {
        float4 v0 = ((const float4*)(v + ((size_t)br0 * T + t) * C))[lane];
        float4 v1 = ((const float4*)(v + ((size_t)br1 * T + t) * C))[lane];
        float4 v2 = ((const float4*)(v + ((size_t)br2 * T + t) * C))[lane];
        float4 v3 = ((const float4*)(v + ((size_t)br3 * T + t) * C))[lane];
        float d0 = dm_lds[rb + 0][t], d1 = dm_lds[rb + 1][t];
        float d2 = dm_lds[rb + 2][t], d3 = dm_lds[rb + 3][t];
        acc0.x = fmaf(d0, v0.x, acc0.x); acc0.y = fmaf(d0, v0.y, acc0.y);
        acc0.z = fmaf(d0, v0.z, acc0.z); acc0.w = fmaf(d0, v0.w, acc0.w);
        acc1.x = fmaf(d1, v1.x, acc1.x); acc1.y = fmaf(d1, v1.y, acc1.y);
        acc1.z = fmaf(d1, v1.z, acc1.z); acc1.w = fmaf(d1, v1.w, acc1.w);
        acc2.x = fmaf(d2, v2.x, acc2.x); acc2.y = fmaf(d2, v2.y, acc2.y);
        acc2.z = fmaf(d2, v2.z, acc2.z); acc2.w = fmaf(d2, v2.w, acc2.w);
        acc3.x = fmaf(d3, v3.x, acc3.x); acc3.y = fmaf(d3, v3.y, acc3.y);
        acc3.z = fmaf(d3, v3.z, acc3.z); acc3.w = fmaf(d3, v3.w, acc3.w);
      }
    }
    float4 y;
    y.x = x0.x + fmaxf(fmaf(a4.x, acc0.x, b4.x), 0.f);
    y.y = x0.y + fmaxf(fmaf(a4.y, acc0.y, b4.y), 0.f);
    y.z = x0.z + fmaxf(fmaf(a4.z, acc0.z, b4.z), 0.f);
    y.w = x0.w + fmaxf(fmaf(a4.w, acc0.w, b4.w), 0.f);
    out4[(size_t)(n0 + rb + 0) * 64 + lane] = y;
    y.x = x1.x + fmaxf(fmaf(a4.x, acc1.x, b4.x), 0.f);
    y.y = x1.y + fmaxf(fmaf(a4.y, acc1.y, b4.y), 0.f);
    y.z = x1.z + fmaxf(fmaf(a4.z, acc1.z, b4.z), 0.f);
    y.w = x1.w + fmaxf(fmaf(a4.w, acc1.w, b4.w), 0.f);
    out4[(size_t)(n0 + rb + 1) * 64 + lane] = y;
    y.x = x2.x + fmaxf(fmaf(a4.x, acc2.x, b4.x), 0.f);
    y.y = x2.y + fmaxf(fmaf(a4.y, acc2.y, b4.y), 0.f);
    y.z = x2.z + fmaxf(fmaf(a4.z, acc2.z, b4.z), 0.f);
    y.w = x2.w + fmaxf(fmaf(a4.w, acc2.w, b4.w), 0.f);
    out4[(size_t)(n0 + rb + 2) * 64 + lane] = y;
    y.x = x3.x + fmaxf(fmaf(a4.x, acc3.x, b4.x), 0.f);
    y.y = x3.y + fmaxf(fmaf(a4.y, acc3.y, b4.y), 0.f);
    y.z = x3.z + fmaxf(fmaf(a4.z, acc3.z, b4.z), 0.f);
    y.w = x3.w + fmaxf(fmaf(a4.w, acc3.w, b4.w), 0.f);
    out4[(size_t)(n0 + rb + 3) * 64 + lane] = y;
  }
}

extern "C" void kernel_launch(void* const* d_in, const int* in_sizes, int n_in,
                              void* d_out, int out_size, void* d_ws, size_t ws_size,
                              hipStream_t stream) {
  const float* xf    = (const float*)d_in[0];
  const int* bids    = (const int*)d_in[1];
  const float* Wq    = (const float*)d_in[2];
  const float* Wk    = (const float*)d_in[3];
  const float* Wp    = (const float*)d_in[4];
  const float* Wv    = (const float*)d_in[5];
  const float* Wke   = (const float*)d_in[6];
  const float* Wqe   = (const float*)d_in[7];
  const float* Wemb  = (const float*)d_in[8];
  const float* Wt    = (const float*)d_in[9];
  const float* Wtr   = (const float*)d_in[10];
  const float* gamma = (const float*)d_in[11];
  const float* beta  = (const float*)d_in[12];
  float* out = (float*)d_out;
  float* ws  = (float*)d_ws;

  float* dm    = ws + OFF_DM;
  float* z     = ws + OFF_Z;
  float* s     = ws + OFF_S;
  float* dmp   = ws + OFF_DMP;
  float* ssp   = ws + OFF_SSP;
  float* keys  = ws + OFF_KEYS;
  float* qrs   = ws + OFF_QRS;
  float* vals  = ws + OFF_VALS;
  float* tm    = ws + OFF_TM;
  float* tp    = ws + OFF_TP;
  float* u     = ws + OFF_U;
  float* v     = ws + OFF_V;
  float* cmb   = ws + OFF_CMB;
  float* bn_a  = ws + OFF_BNA;
  float* bn_b  = ws + OFF_BNB;

  k0_init<<<(ZERO_N + 255) / 256, 256, 0, stream>>>(ws);
  kAB3<<<NP / AB_RPB, 256, 0, stream>>>(xf, bids, Wk, z, s);
  k4a_cmb<<<dim3(5, 32), 256, 0, stream>>>(Wv, Wke, Wqe, Wt, Wemb, Wq, cmb);
  k4b_kqv<<<dim3(BB, 3, 4), 256, 0, stream>>>(cmb, s, z, keys, qrs, vals);
  k4c_att<<<BB, 256, 0, stream>>>(keys, qrs, vals, tm);
  k4d_tp<<<dim3(BB, 4), 256, 0, stream>>>(cmb, s, z, tm, tp);
  k4e_uv<<<dim3(BB, 2, 4), 256, 0, stream>>>(Wp, Wtr, tp, u, v);
  kDE<<<NP / RPB, 256, 0, stream>>>(xf, bids, u, v, dm, dmp, ssp);
  k7_bn<<<1, 256, 0, stream>>>(dmp, ssp, v, gamma, beta, bn_a, bn_b);
  kF_out<<<NP / RPB, 256, 0, stream>>>(xf, bids, dm, v, bn_a, bn_b, out);
}

// Round 19
// 345.410 us; speedup vs baseline: 1.0748x; 1.0748x over previous
//
#include <hip/hip_runtime.h>

#define NP 131072
#define C 256
#define T 16
#define BB 8
constexpr float EPS = 1e-5f;

// ---------------- ws layout (floats) ----------------
constexpr int NT       = NP * T;              // 2,097,152
constexpr int OFF_DM   = 0;                   // dm softmax [N,T]
constexpr int OFF_Z    = NT;                  // z [B,T]
constexpr int OFF_S    = OFF_Z + BB * T;      // s [B,T,C] (unnormalized; rz folded downstream)
constexpr int OFF_DMP  = OFF_S + BB * T * C;  // dmsum partials [8][B*T]
constexpr int OFF_SSP  = OFF_DMP + 8 * BB * T;// sumsq partials [8][C]
constexpr int OFF_KEYS = OFF_SSP + 8 * C;
constexpr int OFF_QRS  = OFF_KEYS + BB * T * C;
constexpr int OFF_VALS = OFF_QRS + BB * T * C;
constexpr int OFF_TM   = OFF_VALS + BB * T * C;
constexpr int OFF_TP   = OFF_TM + BB * T * C;
constexpr int OFF_U    = OFF_TP + BB * T * C;
constexpr int OFF_V    = OFF_U + BB * T * C;
constexpr int OFF_CMB  = OFF_V + BB * T * C;  // 5 x [C,C]
constexpr int OFF_BNA  = OFF_CMB + 5 * C * C; // [C]
constexpr int OFF_BNB  = OFF_BNA + C;         // [C]

constexpr int RPB = 64;       // rows per block for kDE / kF (R15 showed 256 regresses here)
constexpr int AB_RPB = 256;   // kAB3: R12-proven best (121us). R18 prefetch regressed; reverted.
constexpr int ZERO_N = BB * T + BB * T * C + 8 * BB * T + 8 * C;

// reduce-scatter 64 values across the 64 lanes of a wave.
__device__ inline float reduceScatter64(const float (&a)[64], int lane) {
  float b32[32];
  {
    bool hi = (lane & 32) != 0;
#pragma unroll
    for (int i = 0; i < 32; ++i) {
      float mine = hi ? a[i + 32] : a[i];
      float th   = hi ? a[i]      : a[i + 32];
      b32[i] = mine + __shfl_xor(th, 32);
    }
  }
  float b16[16];
  {
    bool hi = (lane & 16) != 0;
#pragma unroll
    for (int i = 0; i < 16; ++i) {
      float mine = hi ? b32[i + 16] : b32[i];
      float th   = hi ? b32[i]      : b32[i + 16];
      b16[i] = mine + __shfl_xor(th, 16);
    }
  }
  float b8[8];
  {
    bool hi = (lane & 8) != 0;
#pragma unroll
    for (int i = 0; i < 8; ++i) {
      float mine = hi ? b16[i + 8] : b16[i];
      float th   = hi ? b16[i]     : b16[i + 8];
      b8[i] = mine + __shfl_xor(th, 8);
    }
  }
  float b4[4];
  {
    bool hi = (lane & 4) != 0;
#pragma unroll
    for (int i = 0; i < 4; ++i) {
      float mine = hi ? b8[i + 4] : b8[i];
      float th   = hi ? b8[i]     : b8[i + 4];
      b4[i] = mine + __shfl_xor(th, 4);
    }
  }
  float b2[2];
  {
    bool hi = (lane & 2) != 0;
#pragma unroll
    for (int i = 0; i < 2; ++i) {
      float mine = hi ? b4[i + 2] : b4[i];
      float th   = hi ? b4[i]     : b4[i + 2];
      b2[i] = mine + __shfl_xor(th, 2);
    }
  }
  bool hi = (lane & 1) != 0;
  float mine = hi ? b2[1] : b2[0];
  float th   = hi ? b2[0] : b2[1];
  return mine + __shfl_xor(th, 1);
}

// ---------------- K0: zero accumulators ----------------
__global__ __launch_bounds__(256) void k0_init(float* __restrict__ ws) {
  int i = blockIdx.x * 256 + threadIdx.x;
  if (i < ZERO_N) ws[OFF_Z + i] = 0.f;
}

// flush helper for boundary blocks
__device__ inline void s_flush(float4 (&acc)[T], int cur_b, int lane,
                               float* __restrict__ s) {
#pragma unroll
  for (int t = 0; t < T; ++t) {
    float* p = s + ((size_t)cur_b * T + t) * C + 4 * lane;
    atomicAdd(p + 0, acc[t].x);
    atomicAdd(p + 1, acc[t].y);
    atomicAdd(p + 2, acc[t].z);
    atomicAdd(p + 3, acc[t].w);
    acc[t] = make_float4(0.f, 0.f, 0.f, 0.f);
  }
}

// ---------------- kAB3: single-x-pass fused e/z/s' (R12 config) ----------------
// 256 threads, AB_RPB=256 (512 blocks, 2.1M s-atomics = saturated floor).
// Plain launch_bounds(256): do NOT add min-waves (R7: forced spill).
__global__ __launch_bounds__(256) void kAB3(const float* __restrict__ xf,
    const int* __restrict__ bids, const float* __restrict__ Wk,
    float* __restrict__ z, float* __restrict__ s) {
  __shared__ float4 wk_sacc[T * 64];    // 16 KB: wk4 in loop; sacc after
  __shared__ float e_lds[AB_RPB][T];    // 16 KB (wave-local rows)
  __shared__ float zred[4][64];         // 1 KB
  __shared__ int bid_lds[AB_RPB];       // 1 KB
  float4* wk4 = wk_sacc;
  float* sacc = (float*)wk_sacc;
  const int tid = threadIdx.x;
  const int n0 = blockIdx.x * AB_RPB;
  for (int i = tid; i < T * 64; i += 256) {
    int t = i >> 6, q = i & 63;
    wk4[i] = make_float4(Wk[(4 * q + 0) * T + t], Wk[(4 * q + 1) * T + t],
                         Wk[(4 * q + 2) * T + t], Wk[(4 * q + 3) * T + t]);
  }
  for (int i = tid; i < AB_RPB; i += 256) bid_lds[i] = bids[n0 + i];
  __syncthreads();
  const int wave = tid >> 6, lane = tid & 63;
  const int rr = lane >> 4, tt = lane & 15;
  const float4* xf4 = (const float4*)xf;
  const bool blockUni = (bid_lds[0] == bid_lds[AB_RPB - 1]);
  const int WROWS = AB_RPB / 4;          // rows per wave = 64

  int cur_b = bid_lds[wave * WROWS + rr];
  float zacc = 0.f;
  float4 acc2[T];
#pragma unroll
  for (int t = 0; t < T; ++t) acc2[t] = make_float4(0.f, 0.f, 0.f, 0.f);
  int cb2 = bid_lds[wave * WROWS];

  for (int stp = 0; stp < WROWS / 4; ++stp) {
    const int rb = wave * WROWS + stp * 4;
    float4 xs[4];
#pragma unroll
    for (int r = 0; r < 4; ++r)
      xs[r] = xf4[(size_t)(n0 + rb + r) * 64 + lane];
    float acc[64];
#pragma unroll
    for (int t = 0; t < T; ++t) {
      float4 w = wk4[t * 64 + lane];
      acc[0 * 16 + t] = xs[0].x * w.x + xs[0].y * w.y + xs[0].z * w.z + xs[0].w * w.w;
      acc[1 * 16 + t] = xs[1].x * w.x + xs[1].y * w.y + xs[1].z * w.z + xs[1].w * w.w;
      acc[2 * 16 + t] = xs[2].x * w.x + xs[2].y * w.y + xs[2].z * w.z + xs[2].w * w.w;
      acc[3 * 16 + t] = xs[3].x * w.x + xs[3].y * w.y + xs[3].z * w.z + xs[3].w * w.w;
    }
    float rv = reduceScatter64(acc, lane);
    float ev = __expf(rv);
    e_lds[rb + rr][tt] = ev;
    if (!blockUni) {
      int b = bid_lds[rb + rr];
      if (b != cur_b) { atomicAdd(&z[cur_b * T + tt], zacc); zacc = 0.f; cur_b = b; }
    }
    zacc += ev;
    bool uni = blockUni || (bid_lds[rb] == cb2 && bid_lds[rb + 3] == cb2);
    if (uni) {
#pragma unroll
      for (int tq = 0; tq < 4; ++tq) {
#pragma unroll
        for (int r = 0; r < 4; ++r) {
          float4 ev4 = ((const float4*)&e_lds[rb + r][0])[tq];
          acc2[tq * 4 + 0].x = fmaf(ev4.x, xs[r].x, acc2[tq * 4 + 0].x);
          acc2[tq * 4 + 0].y = fmaf(ev4.x, xs[r].y, acc2[tq * 4 + 0].y);
          acc2[tq * 4 + 0].z = fmaf(ev4.x, xs[r].z, acc2[tq * 4 + 0].z);
          acc2[tq * 4 + 0].w = fmaf(ev4.x, xs[r].w, acc2[tq * 4 + 0].w);
          acc2[tq * 4 + 1].x = fmaf(ev4.y, xs[r].x, acc2[tq * 4 + 1].x);
          acc2[tq * 4 + 1].y = fmaf(ev4.y, xs[r].y, acc2[tq * 4 + 1].y);
          acc2[tq * 4 + 1].z = fmaf(ev4.y, xs[r].z, acc2[tq * 4 + 1].z);
          acc2[tq * 4 + 1].w = fmaf(ev4.y, xs[r].w, acc2[tq * 4 + 1].w);
          acc2[tq * 4 + 2].x = fmaf(ev4.z, xs[r].x, acc2[tq * 4 + 2].x);
          acc2[tq * 4 + 2].y = fmaf(ev4.z, xs[r].y, acc2[tq * 4 + 2].y);
          acc2[tq * 4 + 2].z = fmaf(ev4.z, xs[r].z, acc2[tq * 4 + 2].z);
          acc2[tq * 4 + 2].w = fmaf(ev4.z, xs[r].w, acc2[tq * 4 + 2].w);
          acc2[tq * 4 + 3].x = fmaf(ev4.w, xs[r].x, acc2[tq * 4 + 3].x);
          acc2[tq * 4 + 3].y = fmaf(ev4.w, xs[r].y, acc2[tq * 4 + 3].y);
          acc2[tq * 4 + 3].z = fmaf(ev4.w, xs[r].z, acc2[tq * 4 + 3].z);
          acc2[tq * 4 + 3].w = fmaf(ev4.w, xs[r].w, acc2[tq * 4 + 3].w);
        }
      }
    } else {
#pragma unroll
      for (int r = 0; r < 4; ++r) {
        int b = bid_lds[rb + r];
        if (b != cb2) { s_flush(acc2, cb2, lane, s); cb2 = b; }
#pragma unroll
        for (int t = 0; t < T; ++t) {
          float ev2 = e_lds[rb + r][t];
          acc2[t].x = fmaf(ev2, xs[r].x, acc2[t].x);
          acc2[t].y = fmaf(ev2, xs[r].y, acc2[t].y);
          acc2[t].z = fmaf(ev2, xs[r].z, acc2[t].z);
          acc2[t].w = fmaf(ev2, xs[r].w, acc2[t].w);
        }
      }
    }
  }
  if (blockUni) zred[wave][lane] = zacc;
  else atomicAdd(&z[cur_b * T + tt], zacc);
  __syncthreads();
  if (blockUni) {
    if (tid < 64) {
      float zt = zred[0][tid] + zred[1][tid] + zred[2][tid] + zred[3][tid];
      zt += __shfl_xor(zt, 16);
      zt += __shfl_xor(zt, 32);
      if (tid < 16) atomicAdd(&z[bid_lds[0] * T + tid], zt);
    }
    for (int i = tid; i < T * C; i += 256) sacc[i] = 0.f;
    __syncthreads();
#pragma unroll
    for (int t = 0; t < T; ++t) {
      float* p = sacc + t * C + 4 * lane;
      atomicAdd(p + 0, acc2[t].x);
      atomicAdd(p + 1, acc2[t].y);
      atomicAdd(p + 2, acc2[t].z);
      atomicAdd(p + 3, acc2[t].w);
    }
    __syncthreads();
    int b0 = bid_lds[0];
    for (int t = 0; t < T; ++t)
      atomicAdd(&s[((size_t)b0 * T + t) * C + tid], sacc[t * C + tid]);
  } else {
    s_flush(acc2, cb2, lane, s);
  }
}

// ---------------- K4a: combined weight mats ----------------
__global__ __launch_bounds__(256) void k4a_cmb(const float* __restrict__ Wv,
    const float* __restrict__ Wke, const float* __restrict__ Wqe,
    const float* __restrict__ Wt, const float* __restrict__ Wemb,
    const float* __restrict__ Wq, float* __restrict__ cmb) {
  int mm = blockIdx.x, r = blockIdx.y;
  const float* A = (mm == 0) ? Wv : (mm == 1) ? Wke : (mm == 2) ? Wqe : Wt;
  const float* Bm = (mm == 4) ? Wemb : Wq;
  bool modeT = (mm == 4);
  __shared__ float a_lds[8 * C];
  int o0 = r * 8;
  for (int i = threadIdx.x; i < 8 * C; i += 256) a_lds[i] = A[o0 * C + i];
  __syncthreads();
  int cp = threadIdx.x;
  float acc[8];
#pragma unroll
  for (int oo = 0; oo < 8; ++oo) acc[oo] = 0.f;
  for (int c = 0; c < C; ++c) {
    float bb = modeT ? Bm[c * C + cp] : Bm[cp * C + c];
#pragma unroll
    for (int oo = 0; oo < 8; ++oo) acc[oo] = fmaf(a_lds[oo * C + c], bb, acc[oo]);
  }
  float* outp = cmb + mm * C * C;
#pragma unroll
  for (int oo = 0; oo < 8; ++oo) outp[(o0 + oo) * C + cp] = acc[oo];
}

// ---------------- K4b: keys/qrs/vals (z-normalization folded in) ----------------
__global__ __launch_bounds__(256) void k4b_kqv(const float* __restrict__ cmb,
    const float* __restrict__ s, const float* __restrict__ z,
    float* __restrict__ keys, float* __restrict__ qrs, float* __restrict__ vals) {
  int b = blockIdx.x, mat = blockIdx.y, q = blockIdx.z;
  const int midx0 = (mat == 0) ? 1 : (mat == 1) ? 2 : 0;
  const float* M = cmb + midx0 * C * C;
  float* outp = (mat == 0) ? keys : (mat == 1) ? qrs : vals;
  __shared__ float s_lds[T * C];
  __shared__ float rz[T];
  if (threadIdx.x < T) rz[threadIdx.x] = 1.f / z[b * T + threadIdx.x];
  __syncthreads();
  for (int i = threadIdx.x; i < T * C; i += 256)
    s_lds[i] = s[(size_t)b * T * C + i] * rz[i >> 8];
  __syncthreads();
  int o = q * 64 + (threadIdx.x & 63);
  int tg = threadIdx.x >> 6;
  float acc[4] = {0.f, 0.f, 0.f, 0.f};
  for (int c = 0; c < C; ++c) {
    float m = M[o * C + c];
#pragma unroll
    for (int tt = 0; tt < 4; ++tt) acc[tt] = fmaf(m, s_lds[(tg * 4 + tt) * C + c], acc[tt]);
  }
#pragma unroll
  for (int tt = 0; tt < 4; ++tt)
    outp[((size_t)b * T + tg * 4 + tt) * C + o] = acc[tt];
}

// ---------------- K4c: token attention + T_middle ----------------
__global__ __launch_bounds__(256) void k4c_att(const float* __restrict__ keys,
    const float* __restrict__ qrs, const float* __restrict__ vals,
    float* __restrict__ tm) {
  int b = blockIdx.x;
  __shared__ float k_lds[T * 257];
  __shared__ float q_lds[T * 257];
  __shared__ float v_lds[T * 257];
  __shared__ float att[T * 17];
  int tid = threadIdx.x;
  for (int i = tid; i < T * C; i += 256) {
    int t = i >> 8, c = i & 255;
    k_lds[t * 257 + c] = keys[((size_t)b * T + t) * C + c];
    q_lds[t * 257 + c] = qrs[((size_t)b * T + t) * C + c];
    v_lds[t * 257 + c] = vals[((size_t)b * T + t) * C + c];
  }
  __syncthreads();
  {
    int t = tid >> 4, s2 = tid & 15;
    float acc = 0.f;
    for (int o = 0; o < C; ++o) acc = fmaf(k_lds[t * 257 + o], q_lds[s2 * 257 + o], acc);
    att[t * 17 + s2] = acc;
  }
  __syncthreads();
  if (tid < T) {
    float m = -1e30f;
    for (int s2 = 0; s2 < T; ++s2) m = fmaxf(m, att[tid * 17 + s2]);
    float sum = 0.f;
    for (int s2 = 0; s2 < T; ++s2) {
      float ee = __expf(att[tid * 17 + s2] - m);
      att[tid * 17 + s2] = ee;
      sum += ee;
    }
    float inv = 1.f / sum;
    for (int s2 = 0; s2 < T; ++s2) att[tid * 17 + s2] *= inv;
  }
  __syncthreads();
  for (int t = 0; t < T; ++t) {
    float acc = 0.f;
#pragma unroll
    for (int s2 = 0; s2 < T; ++s2) acc = fmaf(att[t * 17 + s2], v_lds[s2 * 257 + tid], acc);
    tm[((size_t)b * T + t) * C + tid] = acc;
  }
}

// ---------------- K4d: T_P = At*(s/z) + Ae*Tm ----------------
__global__ __launch_bounds__(256) void k4d_tp(const float* __restrict__ cmb,
    const float* __restrict__ s, const float* __restrict__ z,
    const float* __restrict__ tm, float* __restrict__ tp) {
  int b = blockIdx.x, q = blockIdx.y;
  const float* At = cmb + 3 * C * C;
  const float* Ae = cmb + 4 * C * C;
  __shared__ float s_lds[T * C];
  __shared__ float tm_lds[T * C];
  __shared__ float rz[T];
  if (threadIdx.x < T) rz[threadIdx.x] = 1.f / z[b * T + threadIdx.x];
  __syncthreads();
  for (int i = threadIdx.x; i < T * C; i += 256) {
    s_lds[i] = s[(size_t)b * T * C + i] * rz[i >> 8];
    tm_lds[i] = tm[(size_t)b * T * C + i];
  }
  __syncthreads();
  int o = q * 64 + (threadIdx.x & 63);
  int tg = threadIdx.x >> 6;
  float acc[4] = {0.f, 0.f, 0.f, 0.f};
  for (int c = 0; c < C; ++c) {
    float a1 = At[o * C + c], a2 = Ae[o * C + c];
#pragma unroll
    for (int tt = 0; tt < 4; ++tt) {
      int t = tg * 4 + tt;
      acc[tt] = fmaf(a1, s_lds[t * C + c], fmaf(a2, tm_lds[t * C + c], acc[tt]));
    }
  }
#pragma unroll
  for (int tt = 0; tt < 4; ++tt)
    tp[((size_t)b * T + tg * 4 + tt) * C + o] = acc[tt];
}

// ---------------- K4e: U = Wp*T_P ; V = T_P^T * Wtrans ----------------
__global__ __launch_bounds__(256) void k4e_uv(const float* __restrict__ Wp,
    const float* __restrict__ Wtrans, const float* __restrict__ tp,
    float* __restrict__ u, float* __restrict__ v) {
  int b = blockIdx.x, mat = blockIdx.y, q = blockIdx.z;
  __shared__ float tp_lds[T * C];
  for (int i = threadIdx.x; i < T * C; i += 256) tp_lds[i] = tp[(size_t)b * T * C + i];
  __syncthreads();
  int o = q * 64 + (threadIdx.x & 63);
  int tg = threadIdx.x >> 6;
  float acc[4] = {0.f, 0.f, 0.f, 0.f};
  for (int c = 0; c < C; ++c) {
    float w = mat ? Wtrans[c * C + o] : Wp[o * C + c];
#pragma unroll
    for (int tt = 0; tt < 4; ++tt) acc[tt] = fmaf(w, tp_lds[(tg * 4 + tt) * C + c], acc[tt]);
  }
  float* outp = mat ? v : u;
#pragma unroll
  for (int tt = 0; tt < 4; ++tt)
    outp[((size_t)b * T + tg * 4 + tt) * C + o] = acc[tt];
}

// ---------------- kDE: dm = softmax(x.U) ; xr = dm.V ; sumsq, dmsum (RPB=64) ----------------
__global__ __launch_bounds__(256) void kDE(const float* __restrict__ xf,
    const int* __restrict__ bids, const float* __restrict__ u,
    const float* __restrict__ v, float* __restrict__ dmo,
    float* __restrict__ dmsum_p, float* __restrict__ sumsq_p) {
  __shared__ float4 u4[T * 64];
  __shared__ float4 v4[T * 64];
  __shared__ float4 ss4[4][64];
  __shared__ float zred[4][64];
  __shared__ int bid_lds[RPB];
  const int tid = threadIdx.x;
  const int n0 = blockIdx.x * RPB;
  const int b0 = bids[n0];
  const int part = blockIdx.x & 7;
  for (int i = tid; i < T * 64; i += 256) {
    u4[i] = ((const float4*)(u + (size_t)b0 * T * C))[i];
    v4[i] = ((const float4*)(v + (size_t)b0 * T * C))[i];
  }
  if (tid < RPB) bid_lds[tid] = bids[n0 + tid];
  __syncthreads();
  const int wave = tid >> 6, lane = tid & 63;
  const int rr = lane >> 4, tt = lane & 15;
  const float4* xf4 = (const float4*)xf;
  const bool blockUni = (bid_lds[0] == bid_lds[RPB - 1]);
  float4 sqacc = make_float4(0.f, 0.f, 0.f, 0.f);
  float dmacc = 0.f;
  int cur_b = bid_lds[wave * 16 + rr];
  for (int stp = 0; stp < 4; ++stp) {
    const int rb = wave * 16 + stp * 4;
    float4 x0 = xf4[(size_t)(n0 + rb + 0) * 64 + lane];
    float4 x1 = xf4[(size_t)(n0 + rb + 1) * 64 + lane];
    float4 x2 = xf4[(size_t)(n0 + rb + 2) * 64 + lane];
    float4 x3 = xf4[(size_t)(n0 + rb + 3) * 64 + lane];
    float acc[64];
    bool fast = blockUni || ((bid_lds[rb] == b0) && (bid_lds[rb + 3] == b0));
    if (fast) {
#pragma unroll
      for (int t = 0; t < T; ++t) {
        float4 w = u4[t * 64 + lane];
        acc[0 * 16 + t] = x0.x * w.x + x0.y * w.y + x0.z * w.z + x0.w * w.w;
        acc[1 * 16 + t] = x1.x * w.x + x1.y * w.y + x1.z * w.z + x1.w * w.w;
        acc[2 * 16 + t] = x2.x * w.x + x2.y * w.y + x2.z * w.z + x2.w * w.w;
        acc[3 * 16 + t] = x3.x * w.x + x3.y * w.y + x3.z * w.z + x3.w * w.w;
      }
    } else {
      int br0 = bid_lds[rb + 0], br1 = bid_lds[rb + 1];
      int br2 = bid_lds[rb + 2], br3 = bid_lds[rb + 3];
#pragma unroll
      for (int t = 0; t < T; ++t) {
        float4 w0 = ((const float4*)(u + ((size_t)br0 * T + t) * C))[lane];
        float4 w1 = ((const float4*)(u + ((size_t)br1 * T + t) * C))[lane];
        float4 w2 = ((const float4*)(u + ((size_t)br2 * T + t) * C))[lane];
        float4 w3 = ((const float4*)(u + ((size_t)br3 * T + t) * C))[lane];
        acc[0 * 16 + t] = x0.x * w0.x + x0.y * w0.y + x0.z * w0.z + x0.w * w0.w;
        acc[1 * 16 + t] = x1.x * w1.x + x1.y * w1.y + x1.z * w1.z + x1.w * w1.w;
        acc[2 * 16 + t] = x2.x * w2.x + x2.y * w2.y + x2.z * w2.z + x2.w * w2.w;
        acc[3 * 16 + t] = x3.x * w3.x + x3.y * w3.y + x3.z * w3.z + x3.w * w3.w;
      }
    }
    float S = reduceScatter64(acc, lane);
    float mx = S;
#pragma unroll
    for (int m = 1; m < 16; m <<= 1) mx = fmaxf(mx, __shfl_xor(mx, m));
    float ev = __expf(S - mx);
    float sm = ev;
#pragma unroll
    for (int m = 1; m < 16; m <<= 1) sm += __shfl_xor(sm, m);
    float dmv = ev / sm;
    int row = n0 + rb + rr;
    dmo[(size_t)row * T + tt] = dmv;
    if (!blockUni) {
      int b = bid_lds[rb + rr];
      if (b != cur_b) { atomicAdd(&dmsum_p[part * BB * T + cur_b * T + tt], dmacc); dmacc = 0.f; cur_b = b; }
    }
    dmacc += dmv;
#pragma unroll
    for (int r = 0; r < 4; ++r) {
      int br = blockUni ? b0 : bid_lds[rb + r];
      float4 xr = make_float4(0.f, 0.f, 0.f, 0.f);
      if (br == b0) {
#pragma unroll
        for (int t = 0; t < T; ++t) {
          float d = __shfl(dmv, r * 16 + t);
          float4 vv = v4[t * 64 + lane];
          xr.x = fmaf(d, vv.x, xr.x); xr.y = fmaf(d, vv.y, xr.y);
          xr.z = fmaf(d, vv.z, xr.z); xr.w = fmaf(d, vv.w, xr.w);
        }
      } else {
#pragma unroll
        for (int t = 0; t < T; ++t) {
          float d = __shfl(dmv, r * 16 + t);
          float4 vv = ((const float4*)(v + ((size_t)br * T + t) * C))[lane];
          xr.x = fmaf(d, vv.x, xr.x); xr.y = fmaf(d, vv.y, xr.y);
          xr.z = fmaf(d, vv.z, xr.z); xr.w = fmaf(d, vv.w, xr.w);
        }
      }
      sqacc.x = fmaf(xr.x, xr.x, sqacc.x); sqacc.y = fmaf(xr.y, xr.y, sqacc.y);
      sqacc.z = fmaf(xr.z, xr.z, sqacc.z); sqacc.w = fmaf(xr.w, xr.w, sqacc.w);
    }
  }
  if (blockUni) zred[wave][lane] = dmacc;
  else atomicAdd(&dmsum_p[part * BB * T + cur_b * T + tt], dmacc);
  ss4[wave][lane] = sqacc;
  __syncthreads();
  if (blockUni && tid < 64) {
    float zt = zred[0][tid] + zred[1][tid] + zred[2][tid] + zred[3][tid];
    zt += __shfl_xor(zt, 16);
    zt += __shfl_xor(zt, 32);
    if (tid < 16) atomicAdd(&dmsum_p[part * BB * T + b0 * T + tid], zt);
  }
  {
    int l = tid >> 2, k = tid & 3;
    float vsum = ((const float*)&ss4[0][l])[k] + ((const float*)&ss4[1][l])[k] +
                 ((const float*)&ss4[2][l])[k] + ((const float*)&ss4[3][l])[k];
    atomicAdd(&sumsq_p[part * C + tid], vsum);
  }
}

// ---------------- K7: BN params (folds partials) ----------------
__global__ __launch_bounds__(256) void k7_bn(const float* __restrict__ dmsum_p,
    const float* __restrict__ sumsq_p, const float* __restrict__ v,
    const float* __restrict__ gamma, const float* __restrict__ beta,
    float* __restrict__ bn_a, float* __restrict__ bn_b) {
  int o = threadIdx.x;
  float mean = 0.f;
  for (int i = 0; i < BB * T; ++i) {
    float ds = 0.f;
#pragma unroll
    for (int p = 0; p < 8; ++p) ds += dmsum_p[p * BB * T + i];
    mean = fmaf(ds, v[(size_t)i * C + o], mean);
  }
  mean *= (1.f / NP);
  float ss = 0.f;
#pragma unroll
  for (int p = 0; p < 8; ++p) ss += sumsq_p[p * C + o];
  float var = ss * (1.f / NP) - mean * mean;
  float a = gamma[o] * rsqrtf(var + EPS);
  bn_a[o] = a;
  bn_b[o] = beta[o] - a * mean;
}

// ---------------- kF: out = x_f + relu(a*xr + b) ----------------
__global__ __launch_bounds__(256) void kF_out(const float* __restrict__ xf,
    const int* __restrict__ bids, const float* __restrict__ dm,
    const float* __restrict__ v, const float* __restrict__ bn_a,
    const float* __restrict__ bn_b, float* __restrict__ out) {
  __shared__ float4 v4[T * 64];
  __shared__ float dm_lds[RPB][17];
  __shared__ int bid_lds[RPB];
  const int tid = threadIdx.x;
  const int n0 = blockIdx.x * RPB;
  const int b0 = bids[n0];
  for (int i = tid; i < T * 64; i += 256)
    v4[i] = ((const float4*)(v + (size_t)b0 * T * C))[i];
  {
    float4 d4 = ((const float4*)(dm + (size_t)n0 * T))[tid];
    int r = tid >> 2, c0 = (4 * tid) & 15;
    dm_lds[r][c0] = d4.x; dm_lds[r][c0 + 1] = d4.y;
    dm_lds[r][c0 + 2] = d4.z; dm_lds[r][c0 + 3] = d4.w;
  }
  if (tid < RPB) bid_lds[tid] = bids[n0 + tid];
  __syncthreads();
  const int wave = tid >> 6, lane = tid & 63;
  float4 a4 = ((const float4*)bn_a)[lane];
  float4 b4 = ((const float4*)bn_b)[lane];
  const float4* xf4 = (const float4*)xf;
  float4* out4 = (float4*)out;
  for (int stp = 0; stp < 4; ++stp) {
    const int rb = wave * 16 + stp * 4;
    float4 x0 = xf4[(size_t)(n0 + rb + 0) * 64 + lane];
    float4 x1 = xf4[(size_t)(n0 + rb + 1) * 64 + lane];
    float4 x2 = xf4[(size_t)(n0 + rb + 2) * 64 + lane];
    float4 x3 = xf4[(size_t)(n0 + rb + 3) * 64 + lane];
    float4 acc0 = {0, 0, 0, 0}, acc1 = {0, 0, 0, 0}, acc2 = {0, 0, 0, 0}, acc3 = {0, 0, 0, 0};
    bool fast = (bid_lds[rb] == b0) && (bid_lds[rb + 3] == b0);
    if (fast) {
#pragma unroll
      for (int t = 0; t < T; ++t) {
        float4 vv = v4[t * 64 + lane];
        float d0 = dm_lds[rb + 0][t], d1 = dm_lds[rb + 1][t];
        float d2 = dm_lds[rb + 2][t], d3 = dm_lds[rb + 3][t];
        acc0.x = fmaf(d0, vv.x, acc0.x); acc0.y = fmaf(d0, vv.y, acc0.y);
        acc0.z = fmaf(d0, vv.z, acc0.z); acc0.w = fmaf(d0, vv.w, acc0.w);
        acc1.x = fmaf(d1, vv.x, acc1.x); acc1.y = fmaf(d1, vv.y, acc1.y);
        acc1.z = fmaf(d1, vv.z, acc1.z); acc1.w = fmaf(d1, vv.w, acc1.w);
        acc2.x = fmaf(d2, vv.x, acc2.x); acc2.y = fmaf(d2, vv.y, acc2.y);
        acc2.z = fmaf(d2, vv.z, acc2.z); acc2.w = fmaf(d2, vv.w, acc2.w);
        acc3.x = fmaf(d3, vv.x, acc3.x); acc3.y = fmaf(d3, vv.y, acc3.y);
        acc3.z = fmaf(d3, vv.z, acc3.z); acc3.w = fmaf(d3, vv.w, acc3.w);
      }
    } else {
      int br0 = bid_lds[rb + 0], br1 = bid_lds[rb + 1];
      int br2 = bid_lds[rb + 2], br3 = bid_lds[rb + 3];
#pragma unroll
      for (int t = 0; t < T; ++t) {
        float4 v0 = ((const float4*)(v + ((size_t)br0 * T + t) * C))[lane];
        float4 v1 = ((const float4*)(v + ((size_t)br1 * T + t) * C))[lane];
        float4 v2 = ((const float4*)(v + ((size_t)br2 * T + t) * C))[lane];
        float4 v3 = ((const float4*)(v + ((size_t)br3 * T + t) * C))[lane];
        float d0 = dm_lds[rb + 0][t], d1 = dm_lds[rb + 1][t];
        float d2 = dm_lds[rb + 2][t], d3 = dm_lds[rb + 3][t];
        acc0.x = fmaf(d0, v0.x, acc0.x); acc0.y = fmaf(d0, v0.y, acc0.y);
        acc0.z = fmaf(d0, v0.z, acc0.z); acc0.w = fmaf(d0, v0.w, acc0.w);
        acc1.x = fmaf(d1, v1.x, acc1.x); acc1.y = fmaf(d1, v1.y, acc1.y);
        acc1.z = fmaf(d1, v1.z, acc1.z); acc1.w = fmaf(d1, v1.w, acc1.w);
        acc2.x = fmaf(d2, v2.x, acc2.x); acc2.y = fmaf(d2, v2.y, acc2.y);
        acc2.z = fmaf(d2, v2.z, acc2.z); acc2.w = fmaf(d2, v2.w, acc2.w);
        acc3.x = fmaf(d3, v3.x, acc3.x); acc3.y = fmaf(d3, v3.y, acc3.y);
        acc3.z = fmaf(d3, v3.z, acc3.z); acc3.w = fmaf(d3, v3.w, acc3.w);
      }
    }
    float4 y;
    y.x = x0.x + fmaxf(fmaf(a4.x, acc0.x, b4.x), 0.f);
    y.y = x0.y + fmaxf(fmaf(a4.y, acc0.y, b4.y), 0.f);
    y.z = x0.z + fmaxf(fmaf(a4.z, acc0.z, b4.z), 0.f);
    y.w = x0.w + fmaxf(fmaf(a4.w, acc0.w, b4.w), 0.f);
    out4[(size_t)(n0 + rb + 0) * 64 + lane] = y;
    y.x = x1.x + fmaxf(fmaf(a4.x, acc1.x, b4.x), 0.f);
    y.y = x1.y + fmaxf(fmaf(a4.y, acc1.y, b4.y), 0.f);
    y.z = x1.z + fmaxf(fmaf(a4.z, acc1.z, b4.z), 0.f);
    y.w = x1.w + fmaxf(fmaf(a4.w, acc1.w, b4.w), 0.f);
    out4[(size_t)(n0 + rb + 1) * 64 + lane] = y;
    y.x = x2.x + fmaxf(fmaf(a4.x, acc2.x, b4.x), 0.f);
    y.y = x2.y + fmaxf(fmaf(a4.y, acc2.y, b4.y), 0.f);
    y.z = x2.z + fmaxf(fmaf(a4.z, acc2.z, b4.z), 0.f);
    y.w = x2.w + fmaxf(fmaf(a4.w, acc2.w, b4.w), 0.f);
    out4[(size_t)(n0 + rb + 2) * 64 + lane] = y;
    y.x = x3.x + fmaxf(fmaf(a4.x, acc3.x, b4.x), 0.f);
    y.y = x3.y + fmaxf(fmaf(a4.y, acc3.y, b4.y), 0.f);
    y.z = x3.z + fmaxf(fmaf(a4.z, acc3.z, b4.z), 0.f);
    y.w = x3.w + fmaxf(fmaf(a4.w, acc3.w, b4.w), 0.f);
    out4[(size_t)(n0 + rb + 3) * 64 + lane] = y;
  }
}

extern "C" void kernel_launch(void* const* d_in, const int* in_sizes, int n_in,
                              void* d_out, int out_size, void* d_ws, size_t ws_size,
                              hipStream_t stream) {
  const float* xf    = (const float*)d_in[0];
  const int* bids    = (const int*)d_in[1];
  const float* Wq    = (const float*)d_in[2];
  const float* Wk    = (const float*)d_in[3];
  const float* Wp    = (const float*)d_in[4];
  const float* Wv    = (const float*)d_in[5];
  const float* Wke   = (const float*)d_in[6];
  const float* Wqe   = (const float*)d_in[7];
  const float* Wemb  = (const float*)d_in[8];
  const float* Wt    = (const float*)d_in[9];
  const float* Wtr   = (const float*)d_in[10];
  const float* gamma = (const float*)d_in[11];
  const float* beta  = (const float*)d_in[12];
  float* out = (float*)d_out;
  float* ws  = (float*)d_ws;

  float* dm    = ws + OFF_DM;
  float* z     = ws + OFF_Z;
  float* s     = ws + OFF_S;
  float* dmp   = ws + OFF_DMP;
  float* ssp   = ws + OFF_SSP;
  float* keys  = ws + OFF_KEYS;
  float* qrs   = ws + OFF_QRS;
  float* vals  = ws + OFF_VALS;
  float* tm    = ws + OFF_TM;
  float* tp    = ws + OFF_TP;
  float* u     = ws + OFF_U;
  float* v     = ws + OFF_V;
  float* cmb   = ws + OFF_CMB;
  float* bn_a  = ws + OFF_BNA;
  float* bn_b  = ws + OFF_BNB;

  k0_init<<<(ZERO_N + 255) / 256, 256, 0, stream>>>(ws);
  kAB3<<<NP / AB_RPB, 256, 0, stream>>>(xf, bids, Wk, z, s);
  k4a_cmb<<<dim3(5, 32), 256, 0, stream>>>(Wv, Wke, Wqe, Wt, Wemb, Wq, cmb);
  k4b_kqv<<<dim3(BB, 3, 4), 256, 0, stream>>>(cmb, s, z, keys, qrs, vals);
  k4c_att<<<BB, 256, 0, stream>>>(keys, qrs, vals, tm);
  k4d_tp<<<dim3(BB, 4), 256, 0, stream>>>(cmb, s, z, tm, tp);
  k4e_uv<<<dim3(BB, 2, 4), 256, 0, stream>>>(Wp, Wtr, tp, u, v);
  kDE<<<NP / RPB, 256, 0, stream>>>(xf, bids, u, v, dm, dmp, ssp);
  k7_bn<<<1, 256, 0, stream>>>(dmp, ssp, v, gamma, beta, bn_a, bn_b);
  kF_out<<<NP / RPB, 256, 0, stream>>>(xf, bids, dm, v, bn_a, bn_b, out);
}